// Round 4
// baseline (471.766 us; speedup 1.0000x reference)
//
#include <hip/hip_runtime.h>

#define ALPHA 0.2f

static __device__ __forceinline__ float bf2f(unsigned short u) {
    union { unsigned int i; float f; } v; v.i = ((unsigned int)u) << 16; return v.f;
}
static __device__ __forceinline__ unsigned short f2bf(float f) {
    union { float f; unsigned int i; } v; v.f = f;
    unsigned int x = v.i;
    return (unsigned short)((x + 0x7fffu + ((x >> 16) & 1u)) >> 16);  // RNE
}

// flag=1: float tensors are bf16; flag=0: fp32.
// Even-indexed ushorts of fp32 data are low mantissa halves -> ~30% "sane" as
// bf16; genuine bf16 N(0,1) data -> ~100% sane.
__global__ void classify_dtype_kernel(const unsigned short* __restrict__ xr,
                                      int* __restrict__ flag)
{
    const int lane = threadIdx.x;   // 64 threads
    int cnt = 0;
    #pragma unroll
    for (int j = 0; j < 4; j++) {
        unsigned short u = xr[2 * (lane + 64 * j)];
        float a = fabsf(bf2f(u));
        bool sane = (u == 0) || (a >= 1e-20f && a <= 1e3f);
        cnt += sane ? 1 : 0;
    }
    #pragma unroll
    for (int msk = 32; msk >= 1; msk >>= 1) cnt += __shfl_xor(cnt, msk);
    if (lane == 0) *flag = (cnt >= 192) ? 1 : 0;   // bf16 ~256, fp32 ~77
}

// hid[r][c] = sum_k src[r][k]*w[k][c]  (fp32 LDS operands, fp32 acc, bf16 store)
// s_in[r] = acc_f32[r]·a_in ; s_out[r] = acc_f32[r]·a_out  (pre-rounding acc)
// 256 threads, 32-row tile, thread owns 4 rows x 4 cols. W staged in two
// 64-k fp32 panels so fp32 weights lose no precision.
// src_is_h1: src is the bf16 layer-1 activation living in d_out at offset
// (isbf ? 0 : out_elems) ushorts.
__global__ __launch_bounds__(256)
void gemm_score_kernel(const void* __restrict__ srcv,
                       const void* __restrict__ wv,
                       const void* __restrict__ ainv,
                       const void* __restrict__ aoutv,
                       const int* __restrict__ flag,
                       int src_is_h1,
                       int out_elems,
                       unsigned short* __restrict__ hid,
                       float* __restrict__ s_in,
                       float* __restrict__ s_out,
                       int n)
{
    __shared__ float wS[64][128];   // 32 KB (one k-panel)
    __shared__ float hS[32][132];   // 16.9 KB (+4 pad)
    __shared__ float aS[2][128];    // 1 KB

    const int tid = threadIdx.x;
    const bool isbf = (*flag != 0);

    const unsigned short* src_h;
    const float* src_f = nullptr;
    bool src_bf;
    if (src_is_h1) {
        src_bf = true;
        src_h = (const unsigned short*)srcv + (isbf ? 0 : (size_t)out_elems);
    } else {
        src_bf = isbf;
        src_h = (const unsigned short*)srcv;
        src_f = (const float*)srcv;
    }
    const unsigned short* w_h = (const unsigned short*)wv;
    const float*          w_f = (const float*)wv;

    if (tid < 128) {
        aS[0][tid] = isbf ? bf2f(((const unsigned short*)ainv)[tid])
                          : ((const float*)ainv)[tid];
        aS[1][tid] = isbf ? bf2f(((const unsigned short*)aoutv)[tid])
                          : ((const float*)aoutv)[tid];
    }

    const int tx = tid & 31;          // cols 4*tx .. 4*tx+3
    const int ty = tid >> 5;          // rows 4*ty .. 4*ty+3
    const int c0 = tx * 4;
    const int rbase = blockIdx.x * 32;

    for (int idx = tid; idx < 32 * 128; idx += 256) {
        int rr = idx >> 7, c = idx & 127;
        int r = rbase + rr;
        size_t g = (size_t)r * 128 + c;
        hS[rr][c] = (r < n) ? (src_bf ? bf2f(src_h[g]) : src_f[g]) : 0.f;
    }

    float acc[4][4];
    #pragma unroll
    for (int i = 0; i < 4; i++)
        #pragma unroll
        for (int j = 0; j < 4; j++) acc[i][j] = 0.f;

    for (int panel = 0; panel < 2; panel++) {
        __syncthreads();   // protect wS from previous panel's readers
        for (int idx = tid; idx < 64 * 128; idx += 256) {
            int k = idx >> 7, c = idx & 127;
            size_t g = (size_t)(panel * 64 + k) * 128 + c;
            wS[k][c] = isbf ? bf2f(w_h[g]) : w_f[g];
        }
        __syncthreads();

        #pragma unroll 4
        for (int k = 0; k < 64; k++) {
            float4 wq = *(const float4*)&wS[k][c0];
            #pragma unroll
            for (int rr = 0; rr < 4; rr++) {
                float hv = hS[ty * 4 + rr][panel * 64 + k];
                acc[rr][0] += hv * wq.x;
                acc[rr][1] += hv * wq.y;
                acc[rr][2] += hv * wq.z;
                acc[rr][3] += hv * wq.w;
            }
        }
    }

    #pragma unroll
    for (int rr = 0; rr < 4; rr++) {
        int gr = rbase + ty * 4 + rr;
        if (gr < n) {
            ushort4 hq;
            hq.x = f2bf(acc[rr][0]); hq.y = f2bf(acc[rr][1]);
            hq.z = f2bf(acc[rr][2]); hq.w = f2bf(acc[rr][3]);
            *(ushort4*)&hid[(size_t)gr * 128 + c0] = hq;
        }
    }

    #pragma unroll
    for (int rr = 0; rr < 4; rr++) {
        float pin  = acc[rr][0] * aS[0][c0]     + acc[rr][1] * aS[0][c0 + 1]
                   + acc[rr][2] * aS[0][c0 + 2] + acc[rr][3] * aS[0][c0 + 3];
        float pout = acc[rr][0] * aS[1][c0]     + acc[rr][1] * aS[1][c0 + 1]
                   + acc[rr][2] * aS[1][c0 + 2] + acc[rr][3] * aS[1][c0 + 3];
        #pragma unroll
        for (int msk = 16; msk >= 1; msk >>= 1) {   // reduce over 32 tx lanes
            pin  += __shfl_xor(pin, msk);
            pout += __shfl_xor(pout, msk);
        }
        if (tx == 0) {
            int gr = rbase + ty * 4 + rr;
            if (gr < n) { s_in[gr] = pin; s_out[gr] = pout; }
        }
    }
}

// One wave per node. lanes 0..15: per-edge scores + 16-way softmax shuffles;
// all 64 lanes gather 2 bf16 columns per neighbor row, fp32 accumulate.
// out[node] = relu( sum_k adj*softmax(leakyrelu(s_in+s_out[dst]))*hid[dst] + b )
// final_layer=0: write bf16 h1 into outv at (isbf ? 0 : out_elems) ushorts.
// final_layer=1: write per dtype flag (fp32 float2 or bf16 ushort2) at base.
__global__ __launch_bounds__(256)
void gat_aggregate_kernel(const unsigned short* __restrict__ hid,
                          const float* __restrict__ s_in,
                          const float* __restrict__ s_out,
                          const int* __restrict__ dst,
                          const void* __restrict__ adjv,
                          const void* __restrict__ biasv,
                          const int* __restrict__ flag,
                          void* __restrict__ outv,
                          int final_layer,
                          int out_elems,
                          int n)
{
    const int lane = threadIdx.x & 63;
    const int node = (blockIdx.x * 256 + threadIdx.x) >> 6;
    if (node >= n) return;
    const bool isbf = (*flag != 0);

    float sc = -1e30f;
    int dk = 0;
    float av = 0.f;
    if (lane < 16) {
        int ei = node * 16 + lane;
        dk = dst[ei];
        av = isbf ? bf2f(((const unsigned short*)adjv)[ei])
                  : ((const float*)adjv)[ei];
        float e = s_in[node] + s_out[dk];
        sc = (e > 0.f) ? e : ALPHA * e;            // LeakyReLU(0.2)
    }
    float m = sc;
    #pragma unroll
    for (int msk = 8; msk >= 1; msk >>= 1) m = fmaxf(m, __shfl_xor(m, msk));
    float p = (lane < 16) ? __expf(sc - m) : 0.f;
    float s = p;
    #pragma unroll
    for (int msk = 8; msk >= 1; msk >>= 1) s += __shfl_xor(s, msk);
    float wk = (lane < 16) ? av * p / s : 0.f;     // adj * softmax

    const int c = lane * 2;
    float accx = 0.f, accy = 0.f;
    #pragma unroll
    for (int k = 0; k < 16; k++) {
        float wkk = __shfl(wk, k);
        int   dkk = __shfl(dk, k);
        ushort2 hq = *(const ushort2*)&hid[(size_t)dkk * 128 + c];
        accx += wkk * bf2f(hq.x);
        accy += wkk * bf2f(hq.y);
    }
    float bx = isbf ? bf2f(((const unsigned short*)biasv)[c])
                    : ((const float*)biasv)[c];
    float by = isbf ? bf2f(((const unsigned short*)biasv)[c + 1])
                    : ((const float*)biasv)[c + 1];
    float ox = fmaxf(accx + bx, 0.f);
    float oy = fmaxf(accy + by, 0.f);

    const size_t oidx = (size_t)node * 128 + c;
    if (!final_layer) {
        unsigned short* o = (unsigned short*)outv + (isbf ? 0 : (size_t)out_elems);
        ushort2 ov; ov.x = f2bf(ox); ov.y = f2bf(oy);
        *(ushort2*)&o[oidx] = ov;
    } else if (isbf) {
        ushort2 ov; ov.x = f2bf(ox); ov.y = f2bf(oy);
        *(ushort2*)&((unsigned short*)outv)[oidx] = ov;
    } else {
        *(float2*)&((float*)outv)[oidx] = make_float2(ox, oy);
    }
}

extern "C" void kernel_launch(void* const* d_in, const int* in_sizes, int n_in,
                              void* d_out, int out_size, void* d_ws, size_t ws_size,
                              hipStream_t stream)
{
    const void* x      = d_in[0];
    const int*  dst    = (const int*)d_in[1];
    const void* adj    = d_in[2];
    const void* w1     = d_in[3];
    const void* a_in1  = d_in[4];
    const void* a_out1 = d_in[5];
    const void* b1     = d_in[6];
    const void* w2     = d_in[7];
    const void* a_in2  = d_in[8];
    const void* a_out2 = d_in[9];
    const void* b2     = d_in[10];

    const int N = in_sizes[0] / 128;               // 100000

    // ws: hid bf16 (25.6 MB) | s_in f32 | s_out f32 | dtype flag  = 26.4 MB
    unsigned short* hid   = (unsigned short*)d_ws;
    float*          s_in  = (float*)(hid + (size_t)N * 128);
    float*          s_out = s_in + N;
    int*            flag  = (int*)(s_out + N);

    dim3 blk(256);
    dim3 ggrid((N + 31) / 32);                     // 3125
    dim3 agrid((N + 3) / 4);                       // 25000 (1 node per wave)

    classify_dtype_kernel<<<1, 64, 0, stream>>>((const unsigned short*)x, flag);

    // Layer 1: x -> hid,scores ; aggregate -> h1 (bf16, stored inside d_out)
    gemm_score_kernel<<<ggrid, blk, 0, stream>>>(x,  w1, a_in1, a_out1, flag,
                                                 0, out_size, hid, s_in, s_out, N);
    gat_aggregate_kernel<<<agrid, blk, 0, stream>>>(hid, s_in, s_out, dst, adj, b1,
                                                    flag, d_out, 0, out_size, N);
    // Layer 2: h1 -> hid,scores ; aggregate -> final output (dtype per flag)
    gemm_score_kernel<<<ggrid, blk, 0, stream>>>(d_out, w2, a_in2, a_out2, flag,
                                                 1, out_size, hid, s_in, s_out, N);
    gat_aggregate_kernel<<<agrid, blk, 0, stream>>>(hid, s_in, s_out, dst, adj, b2,
                                                    flag, d_out, 1, out_size, N);
}

// Round 5
// 267.255 us; speedup vs baseline: 1.7652x; 1.7652x over previous
//
#include <hip/hip_runtime.h>

#define ALPHA 0.2f
#define LDA 136   // LDS row stride in shorts (272 B = 17*16: aligned, conflict-balanced)

typedef short bf16x8 __attribute__((ext_vector_type(8)));
typedef float f32x4  __attribute__((ext_vector_type(4)));

static __device__ __forceinline__ float bf2f(unsigned short u) {
    union { unsigned int i; float f; } v; v.i = ((unsigned int)u) << 16; return v.f;
}
static __device__ __forceinline__ unsigned short f2bf(float f) {
    union { float f; unsigned int i; } v; v.f = f;
    unsigned int x = v.i;
    return (unsigned short)((x + 0x7fffu + ((x >> 16) & 1u)) >> 16);  // RNE
}

// One-time: wT[c][k] = bf16(w[k][c]) for w1 (block 0) and w2 (block 1).
__global__ __launch_bounds__(256)
void prep_wT_kernel(const float* __restrict__ w1, const float* __restrict__ w2,
                    unsigned short* __restrict__ wT1, unsigned short* __restrict__ wT2)
{
    __shared__ unsigned short wL[128 * 130];   // +2 pad: conflict-free transpose
    const float* w = blockIdx.x ? w2 : w1;
    unsigned short* wT = blockIdx.x ? wT2 : wT1;
    const int tid = threadIdx.x;

    for (int i = 0; i < 16; i++) {             // 4096 float4 units
        int e = tid + i * 256;
        int k = e >> 5, c0 = (e & 31) * 4;
        float4 v = *(const float4*)&w[k * 128 + c0];
        wL[(c0 + 0) * 130 + k] = f2bf(v.x);
        wL[(c0 + 1) * 130 + k] = f2bf(v.y);
        wL[(c0 + 2) * 130 + k] = f2bf(v.z);
        wL[(c0 + 3) * 130 + k] = f2bf(v.w);
    }
    __syncthreads();
    for (int i = 0; i < 8; i++) {              // 2048 ushort8 units
        int e = tid + i * 256;
        int c = e >> 4, k0 = (e & 15) * 8;
        ushort4 a, b;
        a.x = wL[c * 130 + k0 + 0]; a.y = wL[c * 130 + k0 + 1];
        a.z = wL[c * 130 + k0 + 2]; a.w = wL[c * 130 + k0 + 3];
        b.x = wL[c * 130 + k0 + 4]; b.y = wL[c * 130 + k0 + 5];
        b.z = wL[c * 130 + k0 + 6]; b.w = wL[c * 130 + k0 + 7];
        *(ushort4*)&wT[c * 128 + k0]     = a;
        *(ushort4*)&wT[c * 128 + k0 + 4] = b;
    }
}

// MFMA GEMM + fused score dots.
// hid[r][c] = sum_k src[r][k]*w[k][c]  (bf16 in, fp32 acc, bf16 out)
// s_in/s_out from the fp32 accumulators.
// Block: 256 thr = 4 waves; 64 rows x 128 cols; per wave 16x128 strip.
template <bool SRC_BF>
__global__ __launch_bounds__(256)
void gemm_score_mfma(const void* __restrict__ srcv,
                     const unsigned short* __restrict__ wT,   // [c][k] bf16
                     const float* __restrict__ a_in,
                     const float* __restrict__ a_out,
                     unsigned short* __restrict__ hid,
                     float* __restrict__ s_in,
                     float* __restrict__ s_out,
                     int n)
{
    __shared__ short As[64 * LDA];    // 17408 B
    __shared__ short Bs[128 * LDA];   // 34816 B
    __shared__ float aS[2][128];      // 1024 B

    const int tid = threadIdx.x;
    const int rbase = blockIdx.x * 64;

    if (tid < 128) { aS[0][tid] = a_in[tid]; aS[1][tid] = a_out[tid]; }

    // stage A: 64 rows x 128 k as bf16
    if (SRC_BF) {
        const unsigned short* src = (const unsigned short*)srcv;
        #pragma unroll
        for (int i = 0; i < 8; i++) {
            int e = tid + i * 256;            // 2048 ushort4 units
            int r = e >> 5, c4 = (e & 31) * 4;
            int gr = rbase + r;
            ushort4 v;
            if (gr < n) v = *(const ushort4*)&src[(size_t)gr * 128 + c4];
            else { v.x = v.y = v.z = v.w = 0; }
            *(ushort4*)&As[r * LDA + c4] = v;
        }
    } else {
        const float* src = (const float*)srcv;
        #pragma unroll
        for (int i = 0; i < 8; i++) {
            int e = tid + i * 256;
            int r = e >> 5, c4 = (e & 31) * 4;
            int gr = rbase + r;
            ushort4 u;
            if (gr < n) {
                float4 v = *(const float4*)&src[(size_t)gr * 128 + c4];
                u.x = f2bf(v.x); u.y = f2bf(v.y); u.z = f2bf(v.z); u.w = f2bf(v.w);
            } else { u.x = u.y = u.z = u.w = 0; }
            *(ushort4*)&As[r * LDA + c4] = u;
        }
    }
    // stage B: pre-transposed wT (bf16) -> Bs, 16B vector copies
    #pragma unroll
    for (int i = 0; i < 8; i++) {
        int e = tid + i * 256;                // 2048 int4 units
        int nr = e >> 4, j = (e & 15) * 8;
        int4 v = *(const int4*)&wT[nr * 128 + j];
        *(int4*)&Bs[nr * LDA + j] = v;
    }
    __syncthreads();

    const int lane = tid & 63;
    const int wv = tid >> 6;
    const int m = lane & 15;      // row within tile (A) / col (B,C)
    const int q = lane >> 4;      // quad

    f32x4 acc[8];
    #pragma unroll
    for (int t = 0; t < 8; t++) acc[t] = (f32x4){0.f, 0.f, 0.f, 0.f};

    const short* Abase = &As[(wv * 16 + m) * LDA + q * 8];
    const short* Bbase = &Bs[m * LDA + q * 8];

    #pragma unroll
    for (int ks = 0; ks < 4; ks++) {
        bf16x8 aF = *(const bf16x8*)(Abase + ks * 32);
        #pragma unroll
        for (int t = 0; t < 8; t++) {
            bf16x8 bF = *(const bf16x8*)(Bbase + t * 16 * LDA + ks * 32);
            acc[t] = __builtin_amdgcn_mfma_f32_16x16x32_bf16(aF, bF, acc[t], 0, 0, 0);
        }
    }

    // fused score dots from fp32 accumulators
    float pin[4] = {0.f, 0.f, 0.f, 0.f}, pout[4] = {0.f, 0.f, 0.f, 0.f};
    #pragma unroll
    for (int t = 0; t < 8; t++) {
        float ai = aS[0][t * 16 + m];
        float ao = aS[1][t * 16 + m];
        #pragma unroll
        for (int r = 0; r < 4; r++) {
            pin[r]  += acc[t][r] * ai;
            pout[r] += acc[t][r] * ao;
        }
    }
    #pragma unroll
    for (int msk = 8; msk >= 1; msk >>= 1) {
        #pragma unroll
        for (int r = 0; r < 4; r++) {
            pin[r]  += __shfl_xor(pin[r],  msk);
            pout[r] += __shfl_xor(pout[r], msk);
        }
    }
    if (m == 0) {
        #pragma unroll
        for (int r = 0; r < 4; r++) {
            int g = rbase + wv * 16 + q * 4 + r;
            if (g < n) { s_in[g] = pin[r]; s_out[g] = pout[r]; }
        }
    }

    // epilogue: acc -> As (bf16) -> coalesced global store
    // C layout: row = q*4 + r, col = t*16 + m  (within wave's 16-row strip)
    #pragma unroll
    for (int t = 0; t < 8; t++)
        #pragma unroll
        for (int r = 0; r < 4; r++)
            As[(wv * 16 + q * 4 + r) * LDA + t * 16 + m] = (short)f2bf(acc[t][r]);
    __syncthreads();
    #pragma unroll
    for (int i = 0; i < 4; i++) {
        int e = tid + i * 256;                // 1024 int4 units
        int r = e >> 4, j = (e & 15) * 8;
        int gr = rbase + r;
        if (gr < n) {
            int4 v = *(const int4*)&As[r * LDA + j];
            *(int4*)&hid[(size_t)gr * 128 + j] = v;
        }
    }
}

// One wave per node. lanes 0..15: scores + 16-way softmax shuffles;
// all 64 lanes gather 2 bf16 cols per neighbor row, fp32 accumulate.
template <bool FINAL>
__global__ __launch_bounds__(256)
void gat_aggregate_kernel(const unsigned short* __restrict__ hid,
                          const float* __restrict__ s_in,
                          const float* __restrict__ s_out,
                          const int* __restrict__ dst,
                          const float* __restrict__ adj,
                          const float* __restrict__ bias,
                          void* __restrict__ outv,
                          int n)
{
    const int lane = threadIdx.x & 63;
    const int node = (blockIdx.x * 256 + threadIdx.x) >> 6;
    if (node >= n) return;

    float sc = -1e30f;
    int dk = 0;
    float av = 0.f;
    if (lane < 16) {
        int ei = node * 16 + lane;
        dk = dst[ei];
        av = adj[ei];
        float e = s_in[node] + s_out[dk];
        sc = (e > 0.f) ? e : ALPHA * e;            // LeakyReLU(0.2)
    }
    float m = sc;
    #pragma unroll
    for (int msk = 8; msk >= 1; msk >>= 1) m = fmaxf(m, __shfl_xor(m, msk));
    float p = (lane < 16) ? __expf(sc - m) : 0.f;
    float s = p;
    #pragma unroll
    for (int msk = 8; msk >= 1; msk >>= 1) s += __shfl_xor(s, msk);
    float wk = (lane < 16) ? av * p / s : 0.f;     // adj * softmax

    const int c = lane * 2;
    float accx = 0.f, accy = 0.f;
    #pragma unroll
    for (int k = 0; k < 16; k++) {
        float wkk = __shfl(wk, k);
        int   dkk = __shfl(dk, k);
        ushort2 hq = *(const ushort2*)&hid[(size_t)dkk * 128 + c];
        accx += wkk * bf2f(hq.x);
        accy += wkk * bf2f(hq.y);
    }
    float ox = fmaxf(accx + bias[c],     0.f);
    float oy = fmaxf(accy + bias[c + 1], 0.f);

    const size_t oidx = (size_t)node * 128 + c;
    if (FINAL) {
        *(float2*)&((float*)outv)[oidx] = make_float2(ox, oy);
    } else {
        ushort2 ov; ov.x = f2bf(ox); ov.y = f2bf(oy);
        *(ushort2*)&((unsigned short*)outv)[oidx] = ov;
    }
}

extern "C" void kernel_launch(void* const* d_in, const int* in_sizes, int n_in,
                              void* d_out, int out_size, void* d_ws, size_t ws_size,
                              hipStream_t stream)
{
    const float* x      = (const float*)d_in[0];
    const int*   dst    = (const int*)d_in[1];
    const float* adj    = (const float*)d_in[2];
    const float* w1     = (const float*)d_in[3];
    const float* a_in1  = (const float*)d_in[4];
    const float* a_out1 = (const float*)d_in[5];
    const float* b1     = (const float*)d_in[6];
    const float* w2     = (const float*)d_in[7];
    const float* a_in2  = (const float*)d_in[8];
    const float* a_out2 = (const float*)d_in[9];
    const float* b2     = (const float*)d_in[10];

    const int N = in_sizes[0] / 128;               // 100000

    // ws: hid bf16 (25.6MB) | s_in f32 | s_out f32 | wT1 bf16 | wT2 bf16  ~26.5MB
    unsigned short* hid   = (unsigned short*)d_ws;
    float*          s_in  = (float*)(hid + (size_t)N * 128);
    float*          s_out = s_in + N;
    unsigned short* wT1   = (unsigned short*)(s_out + N);
    unsigned short* wT2   = wT1 + 128 * 128;
    // layer-1 activation h1 (bf16) lives in the upper half of the fp32 d_out
    unsigned short* h1    = (unsigned short*)d_out + out_size;

    dim3 blk(256);
    dim3 ggrid((N + 63) / 64);                     // 1563
    dim3 agrid((N + 3) / 4);                       // 25000 (1 node per wave)

    prep_wT_kernel<<<2, blk, 0, stream>>>(w1, w2, wT1, wT2);

    gemm_score_mfma<false><<<ggrid, blk, 0, stream>>>(x,  wT1, a_in1, a_out1,
                                                      hid, s_in, s_out, N);
    gat_aggregate_kernel<false><<<agrid, blk, 0, stream>>>(hid, s_in, s_out, dst,
                                                           adj, b1, h1, N);
    gemm_score_mfma<true><<<ggrid, blk, 0, stream>>>(h1, wT2, a_in2, a_out2,
                                                     hid, s_in, s_out, N);
    gat_aggregate_kernel<true><<<agrid, blk, 0, stream>>>(hid, s_in, s_out, dst,
                                                          adj, b2, d_out, N);
}